// Round 1
// baseline (47.446 us; speedup 1.0000x reference)
//
#include <hip/hip_runtime.h>
#include <hip/hip_bf16.h>

namespace {

constexpr int KIN  = 32;    // IN_CH
constexpr int KOUT = 64;    // OUT_CH
constexpr int KW   = 9;     // KERNEL
constexpr int KPAD = 4;     // PADDING
constexpr int LIN  = 2048;
constexpr int LPAD = 2056;  // LIN + 2*KPAD
constexpr int JDIM = 288;   // 32 ch * 9 features
constexpr int KTOT = 2592;  // 9 taps * 288

typedef __bf16 bf16x8 __attribute__((ext_vector_type(8)));
typedef float  f32x4  __attribute__((ext_vector_type(4)));

__device__ __forceinline__ unsigned short f2bf(float x) {
    unsigned int u = __float_as_uint(x);
    u += 0x7FFFu + ((u >> 16) & 1u);   // RNE
    return (unsigned short)(u >> 16);
}

// silu + 8 cubic B-spline bases, exact Cox-de Boor replication (f32)
__device__ __forceinline__ void kan_features(float v, float f[9]) {
    f[0] = v / (1.0f + __expf(-v));
    float g[12];
#pragma unroll
    for (int j = 0; j < 12; ++j) g[j] = (float)(j - 3) * 0.4f + (-1.0f);
    float bb[11];
#pragma unroll
    for (int j = 0; j < 11; ++j) bb[j] = (v >= g[j] && v < g[j + 1]) ? 1.0f : 0.0f;
#pragma unroll
    for (int k = 1; k <= 3; ++k) {
        float invd = 1.0f / ((float)k * 0.4f);
#pragma unroll
        for (int j = 0; j + k < 11; ++j) {
            float left  = (v - g[j]) * invd;
            float right = (g[j + k + 1] - v) * invd;
            bb[j] = left * bb[j] + right * bb[j + 1];
        }
    }
#pragma unroll
    for (int c = 0; c < 8; ++c) f[1 + c] = bb[c];
}

__device__ __forceinline__ void gload_lds16(const void* g, void* l) {
    __builtin_amdgcn_global_load_lds(
        (const __attribute__((address_space(1))) void*)g,
        (__attribute__((address_space(3))) void*)l,
        16, 0, 0);
}

// ---- kernel 1: reorder weights -> Wr[o][kappa], kappa = k*288 + i*9 + c ----
__global__ __launch_bounds__(256) void kan_wprep(const float* __restrict__ base_w,
                                                 const float* __restrict__ spline_w,
                                                 const float* __restrict__ spline_scaler,
                                                 unsigned short* __restrict__ Wr) {
    int t = blockIdx.x * 256 + threadIdx.x;
    if (t >= KOUT * KIN * KW) return;
    int k = t % KW;
    int i = (t / KW) % KIN;
    int o = t / (KW * KIN);
    float bw = base_w[t];
    float sc = spline_scaler[t];
    unsigned short* w = Wr + (size_t)o * KTOT + k * JDIM + i * 9;
    w[0] = f2bf(bw);
#pragma unroll
    for (int c = 0; c < 8; ++c) w[1 + c] = f2bf(spline_w[(size_t)t * 8 + c] * sc);
}

// ---- kernel 2: features F2[b][p][j], p = padded position, j = i*9 + c ----
__global__ __launch_bounds__(256) void kan_feat(const float* __restrict__ x,
                                                unsigned short* __restrict__ F2) {
    __shared__ unsigned short tile[8 * JDIM];
    int b  = blockIdx.y;
    int p0 = blockIdx.x * 8;
    int t  = threadIdx.x;
    int i  = t >> 3;   // 0..31
    int dp = t & 7;    // 0..7
    int p  = p0 + dp;
    float v = 0.0f;
    if (p >= KPAD && p < LIN + KPAD) v = x[((size_t)b * KIN + i) * LIN + (p - KPAD)];
    float f[9];
    kan_features(v, f);
#pragma unroll
    for (int c = 0; c < 9; ++c) tile[dp * JDIM + i * 9 + c] = f2bf(f[c]);
    __syncthreads();
    const unsigned int* src = (const unsigned int*)tile;
    unsigned int* dst = (unsigned int*)(F2 + ((size_t)b * LPAD + p0) * JDIM);
    for (int idx = t; idx < 8 * JDIM / 2; idx += 256) dst[idx] = src[idx];
}

// ---- kernel 3: MFMA GEMM  out[b][o][l] = sum_kappa Wr[o][kappa] * U[kappa][b,l] ----
constexpr int BN       = 64;
constexpr int TROW     = 72;    // BN + KW - 1
constexpr int F2COLS   = 296;   // 288 + 8 pad  (592 B rows, conflict-free b128)
constexpr int WCOLS    = 104;   // 96 + 8 pad   (208 B rows)
constexpr int NTILES   = 27;    // 81 chunks of 32, 3 per tile

__global__ __launch_bounds__(256) void kan_gemm(const unsigned short* __restrict__ F2,
                                                const unsigned short* __restrict__ Wr,
                                                float* __restrict__ out) {
    __shared__ unsigned short f2t[TROW * F2COLS];   // 42624 B
    __shared__ unsigned short wt[KOUT * WCOLS];     // 13312 B

    int blk = blockIdx.x;
    int b   = blk >> 5;
    int l0  = (blk & 31) * BN;
    int tid = threadIdx.x;
    int lane = tid & 63;
    int wv   = tid >> 6;
    int lo = lane & 15, hi = lane >> 4;

    // ---- stage F2 window: rows p = l0 + r (r<72), 37 chunks of 16B per row ----
    {
        const char* src_base = (const char*)(F2 + ((size_t)b * LPAD + l0) * JDIM);
        for (int base = 0; base < TROW * 37; base += 256) {
            int idx = base + tid;
            if (idx < TROW * 37) {
                int r = idx / 37;
                int c = idx - r * 37;
                int cr = (c < 36) ? c : 0;  // pad chunk -> harmless valid source
                const char* src = src_base + (size_t)r * (JDIM * 2) + cr * 16;
                unsigned short* dst = f2t + (size_t)(base + (tid & ~63)) * 8;
                gload_lds16(src, dst);
            }
        }
    }

    f32x4 acc[4];
#pragma unroll
    for (int m = 0; m < 4; ++m) acc[m] = (f32x4){0.f, 0.f, 0.f, 0.f};

    for (int t = 0; t < NTILES; ++t) {
        // ---- stage W tile: Wr[o][t*96 .. t*96+95], 13 chunks/row (12 real) ----
        {
            int k0 = t * 96;
            for (int base = 0; base < KOUT * 13; base += 256) {
                int idx = base + tid;
                if (idx < KOUT * 13) {
                    int r = idx / 13;
                    int c = idx - r * 13;
                    int cr = (c < 12) ? c : 0;
                    const char* src = (const char*)(Wr + (size_t)r * KTOT + k0 + cr * 8);
                    unsigned short* dst = wt + (size_t)(base + (tid & ~63)) * 8;
                    gload_lds16(src, dst);
                }
            }
        }
        __syncthreads();   // drains vmcnt -> staged data visible

#pragma unroll
        for (int cc = 0; cc < 3; ++cc) {
            int ch = t * 3 + cc;          // global 32-chunk index 0..80
            int k  = ch / 9;              // conv tap 0..8
            int jb = ch - k * 9;          // j-block 0..8 (32 features each)
            const bf16x8* bp = (const bf16x8*)(f2t + (size_t)(wv * 16 + lo + k) * F2COLS + jb * 32 + hi * 8);
            bf16x8 bf = *bp;
#pragma unroll
            for (int m = 0; m < 4; ++m) {
                const bf16x8* ap = (const bf16x8*)(wt + (size_t)(m * 16 + lo) * WCOLS + cc * 32 + hi * 8);
                acc[m] = __builtin_amdgcn_mfma_f32_16x16x32_bf16(*ap, bf, acc[m], 0, 0, 0);
            }
        }
        __syncthreads();   // all waves done reading wt before next overwrite
    }

    // ---- epilogue: D layout col = lane&15 (n), row = (lane>>4)*4 + reg (o) ----
    float* obase = out + ((size_t)b * KOUT) * LIN + l0 + wv * 16 + lo;
#pragma unroll
    for (int m = 0; m < 4; ++m) {
#pragma unroll
        for (int r = 0; r < 4; ++r) {
            int o = m * 16 + hi * 4 + r;
            obase[(size_t)o * LIN] = acc[m][r];
        }
    }
}

} // namespace

extern "C" void kernel_launch(void* const* d_in, const int* in_sizes, int n_in,
                              void* d_out, int out_size, void* d_ws, size_t ws_size,
                              hipStream_t stream) {
    const float* x             = (const float*)d_in[0];
    const float* base_w        = (const float*)d_in[1];
    const float* spline_w      = (const float*)d_in[2];
    const float* spline_scaler = (const float*)d_in[3];
    float* out = (float*)d_out;

    unsigned short* Wr = (unsigned short*)d_ws;                       // 64*2592*2 = 331776 B
    unsigned short* F2 = (unsigned short*)((char*)d_ws + 331776);     // 16*2056*288*2 B

    kan_wprep<<<(KOUT * KIN * KW + 255) / 256, 256, 0, stream>>>(base_w, spline_w, spline_scaler, Wr);
    kan_feat<<<dim3(LPAD / 8, 16), 256, 0, stream>>>(x, F2);
    kan_gemm<<<512, 256, 0, stream>>>(F2, Wr, out);
}

// Round 2
// 46.565 us; speedup vs baseline: 1.0189x; 1.0189x over previous
//
#include <hip/hip_runtime.h>
#include <hip/hip_bf16.h>

namespace {

constexpr int KIN  = 32;    // IN_CH
constexpr int KOUT = 64;    // OUT_CH
constexpr int KW   = 9;     // KERNEL
constexpr int KPAD = 4;     // PADDING
constexpr int LIN  = 2048;
constexpr int LPAD = 2056;  // LIN + 2*KPAD
constexpr int JDIM = 288;   // 32 ch * 9 features
constexpr int KTOT = 2592;  // 9 taps * 288

typedef __bf16 bf16x8 __attribute__((ext_vector_type(8)));
typedef float  f32x4  __attribute__((ext_vector_type(4)));

__device__ __forceinline__ unsigned short f2bf(float x) {
    unsigned int u = __float_as_uint(x);
    u += 0x7FFFu + ((u >> 16) & 1u);   // RNE
    return (unsigned short)(u >> 16);
}

// silu + 8 cubic B-spline bases, exact Cox-de Boor replication (f32)
__device__ __forceinline__ void kan_features(float v, float f[9]) {
    f[0] = v / (1.0f + __expf(-v));
    float g[12];
#pragma unroll
    for (int j = 0; j < 12; ++j) g[j] = (float)(j - 3) * 0.4f + (-1.0f);
    float bb[11];
#pragma unroll
    for (int j = 0; j < 11; ++j) bb[j] = (v >= g[j] && v < g[j + 1]) ? 1.0f : 0.0f;
#pragma unroll
    for (int k = 1; k <= 3; ++k) {
        float invd = 1.0f / ((float)k * 0.4f);
#pragma unroll
        for (int j = 0; j + k < 11; ++j) {
            float left  = (v - g[j]) * invd;
            float right = (g[j + k + 1] - v) * invd;
            bb[j] = left * bb[j] + right * bb[j + 1];
        }
    }
#pragma unroll
    for (int c = 0; c < 8; ++c) f[1 + c] = bb[c];
}

__device__ __forceinline__ void gload_lds16(const void* g, void* l) {
    __builtin_amdgcn_global_load_lds(
        (const __attribute__((address_space(1))) void*)g,
        (__attribute__((address_space(3))) void*)l,
        16, 0, 0);
}

// ---- kernel 1: reorder weights -> Wr[o][kappa], kappa = k*288 + i*9 + c ----
__global__ __launch_bounds__(256) void kan_wprep(const float* __restrict__ base_w,
                                                 const float* __restrict__ spline_w,
                                                 const float* __restrict__ spline_scaler,
                                                 unsigned short* __restrict__ Wr) {
    int t = blockIdx.x * 256 + threadIdx.x;
    if (t >= KOUT * KIN * KW) return;
    int k = t % KW;
    int i = (t / KW) % KIN;
    int o = t / (KW * KIN);
    float bw = base_w[t];
    float sc = spline_scaler[t];
    unsigned short* w = Wr + (size_t)o * KTOT + k * JDIM + i * 9;
    w[0] = f2bf(bw);
#pragma unroll
    for (int c = 0; c < 8; ++c) w[1 + c] = f2bf(spline_w[(size_t)t * 8 + c] * sc);
}

// ---- kernel 2: features F2[b][p][j], p = padded position, j = i*9 + c ----
__global__ __launch_bounds__(256) void kan_feat(const float* __restrict__ x,
                                                unsigned short* __restrict__ F2) {
    __shared__ unsigned short tile[8 * JDIM];
    int b  = blockIdx.y;
    int p0 = blockIdx.x * 8;
    int t  = threadIdx.x;
    int i  = t >> 3;   // 0..31
    int dp = t & 7;    // 0..7
    int p  = p0 + dp;
    float v = 0.0f;
    if (p >= KPAD && p < LIN + KPAD) v = x[((size_t)b * KIN + i) * LIN + (p - KPAD)];
    float f[9];
    kan_features(v, f);
#pragma unroll
    for (int c = 0; c < 9; ++c) tile[dp * JDIM + i * 9 + c] = f2bf(f[c]);
    __syncthreads();
    const unsigned int* src = (const unsigned int*)tile;
    unsigned int* dst = (unsigned int*)(F2 + ((size_t)b * LPAD + p0) * JDIM);
    for (int idx = t; idx < 8 * JDIM / 2; idx += 256) dst[idx] = src[idx];
}

// ---- kernel 3: MFMA GEMM, BN=128, 512 threads, W double-buffered ----
constexpr int BN      = 128;
constexpr int TROW    = 136;   // BN + KW - 1
constexpr int F2COLS  = 296;   // 592 B rows (148 dw, step 20 mod 32 -> ~2-way max)
constexpr int WCOLS   = 104;   // 208 B rows (52 dw, step 20 mod 32)
constexpr int NTILES  = 27;    // 81 chunks of K=32, 3 per tile (96 kappa)
constexpr int FCHUNKS = 37;    // 16B chunks per F2 LDS row (36 real + 1 pad)

__global__ __launch_bounds__(512) void kan_gemm(const unsigned short* __restrict__ F2,
                                                const unsigned short* __restrict__ Wr,
                                                float* __restrict__ out) {
    __shared__ unsigned short f2t[TROW * F2COLS];     // 80512 B
    __shared__ unsigned short wt[2][KOUT * WCOLS];    // 2 x 13312 B

    int tid  = threadIdx.x;
    int lane = tid & 63;
    int wv   = tid >> 6;
    int lo = lane & 15, hi = lane >> 4;
    int wm = wv >> 2;      // 0..1 : o-half
    int wn = wv & 3;       // 0..3 : l-quarter

    int blk = blockIdx.x;
    int b   = blk >> 4;
    int l0  = (blk & 15) * BN;

    // ---- prologue: stage F2 window (136 rows x 37 chunks) ----
    {
        const char* fsrc = (const char*)(F2 + ((size_t)b * LPAD + l0) * JDIM);
        for (int base = 0; base < TROW * FCHUNKS; base += 512) {
            int idx = base + tid;
            if (idx < TROW * FCHUNKS) {
                int r = idx / FCHUNKS;
                int c = idx - r * FCHUNKS;
                int cr = (c < 36) ? c : 0;   // pad chunk -> harmless valid source
                gload_lds16(fsrc + (size_t)r * (JDIM * 2) + cr * 16,
                            f2t + (size_t)(base + (tid & ~63)) * 8);
            }
        }
    }

    // W tile staging: 64 rows x 13 chunks = 832 slots; threads<320 issue 2, rest 1
    auto stageW = [&](int t, unsigned short* dst) {
        int k0 = t * 96;
        {
            int idx = tid;
            int r = idx / 13, c = idx - r * 13;
            int cr = (c < 12) ? c : 0;
            gload_lds16((const char*)(Wr + (size_t)r * KTOT + k0 + cr * 8),
                        dst + (size_t)(tid & ~63) * 8);
        }
        if (tid < 320) {
            int idx = 512 + tid;
            int r = idx / 13, c = idx - r * 13;
            int cr = (c < 12) ? c : 0;
            gload_lds16((const char*)(Wr + (size_t)r * KTOT + k0 + cr * 8),
                        dst + (size_t)(512 + (tid & ~63)) * 8);
        }
    };

    stageW(0, wt[0]);
    asm volatile("s_waitcnt vmcnt(0)" ::: "memory");
    __builtin_amdgcn_sched_barrier(0);
    __builtin_amdgcn_s_barrier();
    __builtin_amdgcn_sched_barrier(0);

    f32x4 acc[2][2];
#pragma unroll
    for (int m = 0; m < 2; ++m)
#pragma unroll
        for (int n = 0; n < 2; ++n) acc[m][n] = (f32x4){0.f, 0.f, 0.f, 0.f};

    const int aoff = (wm * 32 + lo) * WCOLS + hi * 8;       // m=0 A row base
    const int boff = (wn * 32 + lo) * F2COLS + hi * 8;      // n=0 B row base

    for (int t = 0; t < NTILES; ++t) {
        int cur = t & 1;
        if (t + 1 < NTILES) {
            stageW(t + 1, wt[cur ^ 1]);
            if (wv < 5) asm volatile("s_waitcnt vmcnt(2)" ::: "memory");
            else        asm volatile("s_waitcnt vmcnt(1)" ::: "memory");
        } else {
            asm volatile("s_waitcnt vmcnt(0)" ::: "memory");
        }
        __builtin_amdgcn_sched_barrier(0);
        __builtin_amdgcn_s_barrier();
        __builtin_amdgcn_sched_barrier(0);

        const unsigned short* wbase = wt[cur];
        int ch0 = t * 3;
        int k0  = ch0 / 9;
        int j0  = ch0 - k0 * 9;
#pragma unroll
        for (int cc = 0; cc < 3; ++cc) {
            int jj  = j0 + cc;
            int kk  = (jj >= 9) ? (k0 + 1) : k0;
            int jbb = (jj >= 9) ? (jj - 9) : jj;
            bf16x8 a0 = *(const bf16x8*)(wbase + aoff + cc * 32);
            bf16x8 a1 = *(const bf16x8*)(wbase + aoff + 16 * WCOLS + cc * 32);
            bf16x8 b0 = *(const bf16x8*)(f2t + boff + kk * F2COLS + jbb * 32);
            bf16x8 b1 = *(const bf16x8*)(f2t + boff + (16 + kk) * F2COLS + jbb * 32);
            acc[0][0] = __builtin_amdgcn_mfma_f32_16x16x32_bf16(a0, b0, acc[0][0], 0, 0, 0);
            acc[0][1] = __builtin_amdgcn_mfma_f32_16x16x32_bf16(a0, b1, acc[0][1], 0, 0, 0);
            acc[1][0] = __builtin_amdgcn_mfma_f32_16x16x32_bf16(a1, b0, acc[1][0], 0, 0, 0);
            acc[1][1] = __builtin_amdgcn_mfma_f32_16x16x32_bf16(a1, b1, acc[1][1], 0, 0, 0);
        }
        __builtin_amdgcn_sched_barrier(0);
        __builtin_amdgcn_s_barrier();
        __builtin_amdgcn_sched_barrier(0);
    }

    // ---- epilogue: D layout col = lane&15 (l), row = (lane>>4)*4 + reg (o) ----
#pragma unroll
    for (int m = 0; m < 2; ++m) {
#pragma unroll
        for (int n = 0; n < 2; ++n) {
            int oo   = wm * 32 + m * 16 + hi * 4;
            int lcol = l0 + wn * 32 + n * 16 + lo;
            float* op = out + ((size_t)b * KOUT + oo) * LIN + lcol;
#pragma unroll
            for (int r = 0; r < 4; ++r) op[(size_t)r * LIN] = acc[m][n][r];
        }
    }
}

} // namespace

extern "C" void kernel_launch(void* const* d_in, const int* in_sizes, int n_in,
                              void* d_out, int out_size, void* d_ws, size_t ws_size,
                              hipStream_t stream) {
    const float* x             = (const float*)d_in[0];
    const float* base_w        = (const float*)d_in[1];
    const float* spline_w      = (const float*)d_in[2];
    const float* spline_scaler = (const float*)d_in[3];
    float* out = (float*)d_out;

    unsigned short* Wr = (unsigned short*)d_ws;                       // 64*2592*2 = 331776 B
    unsigned short* F2 = (unsigned short*)((char*)d_ws + 331776);     // 16*2056*288*2 B

    kan_wprep<<<(KOUT * KIN * KW + 255) / 256, 256, 0, stream>>>(base_w, spline_w, spline_scaler, Wr);
    kan_feat<<<dim3(LPAD / 8, 16), 256, 0, stream>>>(x, F2);
    kan_gemm<<<256, 512, 0, stream>>>(F2, Wr, out);
}

// Round 3
// 37.102 us; speedup vs baseline: 1.2788x; 1.2551x over previous
//
#include <hip/hip_runtime.h>
#include <hip/hip_bf16.h>

namespace {

constexpr int KIN  = 32;    // IN_CH
constexpr int KOUT = 64;    // OUT_CH
constexpr int KW   = 9;     // KERNEL
constexpr int KPAD = 4;     // PADDING
constexpr int LIN  = 2048;
constexpr int JDIM = 288;   // 32 ch * 9 features
constexpr int KTOT = 2592;  // 9 taps * 288

typedef __bf16 bf16x8 __attribute__((ext_vector_type(8)));
typedef float  f32x4  __attribute__((ext_vector_type(4)));

__device__ __forceinline__ unsigned short f2bf(float x) {
    unsigned int u = __float_as_uint(x);
    u += 0x7FFFu + ((u >> 16) & 1u);   // RNE
    return (unsigned short)(u >> 16);
}

__device__ __forceinline__ void gload_lds16(const void* g, void* l) {
    __builtin_amdgcn_global_load_lds(
        (const __attribute__((address_space(1))) void*)g,
        (__attribute__((address_space(3))) void*)l,
        16, 0, 0);
}

// ---- kernel 1: reorder weights -> Wr[o][kappa], kappa = k*288 + i*9 + c ----
__global__ __launch_bounds__(256) void kan_wprep(const float* __restrict__ base_w,
                                                 const float* __restrict__ spline_w,
                                                 const float* __restrict__ spline_scaler,
                                                 unsigned short* __restrict__ Wr) {
    int t = blockIdx.x * 256 + threadIdx.x;
    if (t >= KOUT * KIN * KW) return;
    int k = t % KW;
    int i = (t / KW) % KIN;
    int o = t / (KW * KIN);
    float bw = base_w[t];
    float sc = spline_scaler[t];
    unsigned short* w = Wr + (size_t)o * KTOT + k * JDIM + i * 9;
    w[0] = f2bf(bw);
#pragma unroll
    for (int c = 0; c < 8; ++c) w[1 + c] = f2bf(spline_w[(size_t)t * 8 + c] * sc);
}

// ---- kernel 2: fused features + MFMA GEMM ----
// out[b][o][l] = sum_{k,i,c} feat_c(xpad[b][i][l+k]) * Wr[o][k*288+i*9+c]
constexpr int BN      = 128;
constexpr int TROW    = 136;   // BN + KW - 1
constexpr int F2COLS  = 296;   // 592 B rows (148 dw, stride 20 mod 32)
constexpr int WCOLS   = 104;   // 208 B rows (52 dw, stride 20 mod 32)
constexpr int NTILES  = 27;    // 81 K-chunks of 32, 3 per tile

__global__ __launch_bounds__(512) void kan_fused(const float* __restrict__ x,
                                                 const unsigned short* __restrict__ Wr,
                                                 float* __restrict__ out) {
    __shared__ unsigned short f2t[TROW * F2COLS];      // 80512 B
    __shared__ unsigned short wt[3][KOUT * WCOLS];     // 3 x 13312 B

    int tid  = threadIdx.x;
    int lane = tid & 63;
    int wv   = tid >> 6;
    int lo = lane & 15, hi = lane >> 4;
    int wm = wv >> 2;      // 0..1 : o-half
    int wn = wv & 3;       // 0..3 : l-quarter

    int blk = blockIdx.x;
    int b   = blk >> 4;
    int l0  = (blk & 15) * BN;

    // W tile staging: 64 rows x 13 chunks = 832 slots (chunk 12 = dup pad)
    auto stageW = [&](int t) {
        unsigned short* dst = wt[t % 3];
        int k0 = t * 96;
        {
            int idx = tid;
            int r = idx / 13, c = idx - r * 13;
            int cr = (c < 12) ? c : 0;
            gload_lds16((const char*)(Wr + (size_t)r * KTOT + k0 + cr * 8),
                        dst + (size_t)(tid & ~63) * 8);
        }
        if (tid < 320) {
            int idx = 512 + tid;
            int r = idx / 13, c = idx - r * 13;
            int cr = (c < 12) ? c : 0;
            gload_lds16((const char*)(Wr + (size_t)r * KTOT + k0 + cr * 8),
                        dst + (size_t)(512 + (tid & ~63)) * 8);
        }
    };

    stageW(0);
    stageW(1);

    // ---- zero f2t (5032 x 16B chunks) ----
    {
        f32x4 z = (f32x4){0.f, 0.f, 0.f, 0.f};
        for (int c = tid; c < TROW * F2COLS / 8; c += 512)
            *(f32x4*)(f2t + (size_t)c * 8) = z;
    }
    asm volatile("s_waitcnt lgkmcnt(0)" ::: "memory");
    __builtin_amdgcn_sched_barrier(0);
    __builtin_amdgcn_s_barrier();
    __builtin_amdgcn_sched_barrier(0);

    // ---- features: silu + 4-support closed-form cubic B-spline, scatter to LDS ----
    // unit = i*TROW + r  (consecutive tid -> consecutive r -> coalesced x reads)
#pragma unroll
    for (int pass = 0; pass < 9; ++pass) {
        int unit = pass * 512 + tid;
        if (unit < TROW * KIN) {
            int i = unit / TROW;
            int r = unit - i * TROW;
            int gx = l0 + r - KPAD;
            float v = 0.f;
            if (gx >= 0 && gx < LIN) v = x[((size_t)b * KIN + i) * LIN + gx];
            unsigned short* row = f2t + (size_t)r * F2COLS + i * 9;
            // silu
            row[0] = f2bf(v / (1.f + __expf(-v)));
            // B-spline cell + fraction (knots at -2.2 + 0.4*j)
            float t5 = (v + 2.2f) * 2.5f;
            float mf = floorf(t5);
            int   m  = (int)mf;           // valid cells 0..10; others auto-skip below
            float u  = t5 - mf;
            float u2 = u * u, u3 = u2 * u;
            float w  = 1.f - u;
            float P0 = u3 * (1.f / 6.f);
            float P3 = w * w * w * (1.f / 6.f);
            float P1 = (1.f / 6.f) + 0.5f * u + 0.5f * u2 - 0.5f * u3;
            float P2 = (4.f / 6.f) - u2 + 0.5f * u3;
            int c0 = m - 3;
            // basis c = piece_{m-c}(u); nonzero for c in [m-3, m] ∩ [0,7]
            if ((unsigned)(c0 + 0) <= 7u) row[1 + c0 + 0] = f2bf(P3);
            if ((unsigned)(c0 + 1) <= 7u) row[1 + c0 + 1] = f2bf(P2);
            if ((unsigned)(c0 + 2) <= 7u) row[1 + c0 + 2] = f2bf(P1);
            if ((unsigned)(c0 + 3) <= 7u) row[1 + c0 + 3] = f2bf(P0);
        }
    }
    asm volatile("s_waitcnt lgkmcnt(0)" ::: "memory");
    __builtin_amdgcn_sched_barrier(0);
    __builtin_amdgcn_s_barrier();
    __builtin_amdgcn_sched_barrier(0);

    f32x4 acc[2][2];
#pragma unroll
    for (int m = 0; m < 2; ++m)
#pragma unroll
        for (int n = 0; n < 2; ++n) acc[m][n] = (f32x4){0.f, 0.f, 0.f, 0.f};

    const int aoff = (wm * 32 + lo) * WCOLS + hi * 8;       // A (W) m=0 base
    const int boff = (wn * 32 + lo) * F2COLS + hi * 8;      // B (F) n=0 base

    for (int t = 0; t < NTILES; ++t) {
        // ensure stage(t) landed (everyone waits own loads, then barrier)
        if (t == NTILES - 1) {
            asm volatile("s_waitcnt vmcnt(0)" ::: "memory");
        } else if (wv < 5) {
            asm volatile("s_waitcnt vmcnt(2)" ::: "memory");
        } else {
            asm volatile("s_waitcnt vmcnt(1)" ::: "memory");
        }
        __builtin_amdgcn_sched_barrier(0);
        __builtin_amdgcn_s_barrier();
        __builtin_amdgcn_sched_barrier(0);
        // barrier(t) also guarantees all waves finished compute(t-1), whose
        // buffer (t-1)%3 == (t+2)%3 is what stage(t+2) overwrites.
        if (t + 2 < NTILES) stageW(t + 2);

        const unsigned short* wbase = wt[t % 3];
        int ch0 = t * 3;
        int k0  = ch0 / 9;
        int j0  = ch0 - k0 * 9;
#pragma unroll
        for (int cc = 0; cc < 3; ++cc) {
            int jj  = j0 + cc;
            int kk  = (jj >= 9) ? (k0 + 1) : k0;
            int jbb = (jj >= 9) ? (jj - 9) : jj;
            bf16x8 a0 = *(const bf16x8*)(wbase + aoff + cc * 32);
            bf16x8 a1 = *(const bf16x8*)(wbase + aoff + 16 * WCOLS + cc * 32);
            bf16x8 b0 = *(const bf16x8*)(f2t + boff + kk * F2COLS + jbb * 32);
            bf16x8 b1 = *(const bf16x8*)(f2t + boff + (16 + kk) * F2COLS + jbb * 32);
            acc[0][0] = __builtin_amdgcn_mfma_f32_16x16x32_bf16(a0, b0, acc[0][0], 0, 0, 0);
            acc[0][1] = __builtin_amdgcn_mfma_f32_16x16x32_bf16(a0, b1, acc[0][1], 0, 0, 0);
            acc[1][0] = __builtin_amdgcn_mfma_f32_16x16x32_bf16(a1, b0, acc[1][0], 0, 0, 0);
            acc[1][1] = __builtin_amdgcn_mfma_f32_16x16x32_bf16(a1, b1, acc[1][1], 0, 0, 0);
        }
    }

    // ---- epilogue: D layout col = lane&15 (l), row = (lane>>4)*4 + reg (o) ----
#pragma unroll
    for (int m = 0; m < 2; ++m) {
#pragma unroll
        for (int n = 0; n < 2; ++n) {
            int oo   = wm * 32 + m * 16 + hi * 4;
            int lcol = l0 + wn * 32 + n * 16 + lo;
            float* op = out + ((size_t)b * KOUT + oo) * LIN + lcol;
#pragma unroll
            for (int r = 0; r < 4; ++r) op[(size_t)r * LIN] = acc[m][n][r];
        }
    }
}

} // namespace

extern "C" void kernel_launch(void* const* d_in, const int* in_sizes, int n_in,
                              void* d_out, int out_size, void* d_ws, size_t ws_size,
                              hipStream_t stream) {
    const float* x             = (const float*)d_in[0];
    const float* base_w        = (const float*)d_in[1];
    const float* spline_w      = (const float*)d_in[2];
    const float* spline_scaler = (const float*)d_in[3];
    float* out = (float*)d_out;

    unsigned short* Wr = (unsigned short*)d_ws;   // 64*2592*2 = 331776 B

    kan_wprep<<<(KOUT * KIN * KW + 255) / 256, 256, 0, stream>>>(base_w, spline_w, spline_scaler, Wr);
    kan_fused<<<256, 512, 0, stream>>>(x, Wr, out);
}

// Round 4
// 30.205 us; speedup vs baseline: 1.5708x; 1.2283x over previous
//
#include <hip/hip_runtime.h>
#include <hip/hip_bf16.h>

namespace {

constexpr int KIN  = 32;    // IN_CH
constexpr int KOUT = 64;    // OUT_CH
constexpr int KW   = 9;     // KERNEL
constexpr int KPAD = 4;     // PADDING
constexpr int LIN  = 2048;
constexpr int JDIM = 288;   // 32 ch * 9 features
constexpr int KTOT = 2592;  // 9 taps * 288

typedef __bf16 bf16x8 __attribute__((ext_vector_type(8)));
typedef float  f32x4  __attribute__((ext_vector_type(4)));

__device__ __forceinline__ unsigned short f2bf(float x) {
    unsigned int u = __float_as_uint(x);
    u += 0x7FFFu + ((u >> 16) & 1u);   // RNE
    return (unsigned short)(u >> 16);
}

__device__ __forceinline__ void gload_lds16(const void* g, void* l) {
    __builtin_amdgcn_global_load_lds(
        (const __attribute__((address_space(1))) void*)g,
        (__attribute__((address_space(3))) void*)l,
        16, 0, 0);
}

// ---- kernel 1: reorder weights -> Wr[o][kappa], kappa = k*288 + i*9 + c ----
__global__ __launch_bounds__(256) void kan_wprep(const float* __restrict__ base_w,
                                                 const float* __restrict__ spline_w,
                                                 const float* __restrict__ spline_scaler,
                                                 unsigned short* __restrict__ Wr) {
    int t = blockIdx.x * 256 + threadIdx.x;
    if (t >= KOUT * KIN * KW) return;
    int k = t % KW;
    int i = (t / KW) % KIN;
    int o = t / (KW * KIN);
    float bw = base_w[t];
    float sc = spline_scaler[t];
    unsigned short* w = Wr + (size_t)o * KTOT + k * JDIM + i * 9;
    w[0] = f2bf(bw);
#pragma unroll
    for (int c = 0; c < 8; ++c) w[1 + c] = f2bf(spline_w[(size_t)t * 8 + c] * sc);
}

// ---- kernel 2: fused features + MFMA GEMM, BN=64, 256 thr, 2 blocks/CU ----
constexpr int BN      = 64;
constexpr int TROW    = 72;    // BN + KW - 1
constexpr int F2COLS  = 296;   // 592 B rows (148 dw, stride 20 mod 32 -> conflict-free)
constexpr int WCOLS   = 104;   // 208 B rows (52 dw, stride 20 mod 32)
constexpr int NTILES  = 27;    // 81 K-chunks of 32, 3 per tile

__global__ __launch_bounds__(256) void kan_fused(const float* __restrict__ x,
                                                 const unsigned short* __restrict__ Wr,
                                                 float* __restrict__ out) {
    __shared__ unsigned short f2t[TROW * F2COLS];      // 42624 B
    __shared__ unsigned short wt[2][KOUT * WCOLS];     // 2 x 13312 B  (total 69.2 KB)

    int tid  = threadIdx.x;
    int lane = tid & 63;
    int wv   = tid >> 6;
    int lo = lane & 15, hi = lane >> 4;
    int wm = wv >> 1;      // 0..1 : o-half (32)
    int wn = wv & 1;       // 0..1 : l-half (32)

    int blk = blockIdx.x;
    int b   = blk >> 5;
    int l0  = (blk & 31) * BN;

    // W tile staging: 64 rows x 13 chunks = 832 slots (chunk 12 = dup pad)
    auto stageW = [&](int t) {
        unsigned short* dst = wt[t & 1];
        int k0 = t * 96;
#pragma unroll
        for (int s = 0; s < 832; s += 256) {
            int idx = s + tid;
            if (idx < 832) {
                int r = idx / 13, c = idx - r * 13;
                int cr = (c < 12) ? c : 0;
                gload_lds16((const char*)(Wr + (size_t)r * KTOT + k0 + cr * 8),
                            dst + (size_t)(s + (tid & ~63)) * 8);
            }
        }
    };

    stageW(0);   // overlaps with zero + feature phase below

    // ---- zero f2t (2664 x 16B chunks) ----
    {
        f32x4 z = (f32x4){0.f, 0.f, 0.f, 0.f};
        for (int c = tid; c < TROW * F2COLS / 8; c += 256)
            *(f32x4*)(f2t + (size_t)c * 8) = z;
    }
    asm volatile("s_waitcnt lgkmcnt(0)" ::: "memory");
    __builtin_amdgcn_sched_barrier(0);
    __builtin_amdgcn_s_barrier();
    __builtin_amdgcn_sched_barrier(0);

    // ---- features: silu + closed-form cubic B-spline, scatter to LDS ----
    // unit = i*TROW + r ; 2304 units = 9 exact passes of 256
#pragma unroll
    for (int pass = 0; pass < 9; ++pass) {
        int unit = pass * 256 + tid;
        int i = unit / TROW;
        int r = unit - i * TROW;
        int gx = l0 + r - KPAD;
        float v = 0.f;
        if (gx >= 0 && gx < LIN) v = x[((size_t)b * KIN + i) * LIN + gx];
        unsigned short* row = f2t + (size_t)r * F2COLS + i * 9;
        row[0] = f2bf(v / (1.f + __expf(-v)));             // silu
        float t5 = (v + 2.2f) * 2.5f;                       // knots at -2.2 + 0.4*j
        float mf = floorf(t5);
        int   m  = (int)mf;
        float u  = t5 - mf;
        float u2 = u * u, u3 = u2 * u;
        float w  = 1.f - u;
        float P0 = u3 * (1.f / 6.f);
        float P3 = w * w * w * (1.f / 6.f);
        float P1 = (1.f / 6.f) + 0.5f * u + 0.5f * u2 - 0.5f * u3;
        float P2 = (4.f / 6.f) - u2 + 0.5f * u3;
        int c0 = m - 3;
        if ((unsigned)(c0 + 0) <= 7u) row[1 + c0 + 0] = f2bf(P3);
        if ((unsigned)(c0 + 1) <= 7u) row[1 + c0 + 1] = f2bf(P2);
        if ((unsigned)(c0 + 2) <= 7u) row[1 + c0 + 2] = f2bf(P1);
        if ((unsigned)(c0 + 3) <= 7u) row[1 + c0 + 3] = f2bf(P0);
    }
    asm volatile("s_waitcnt lgkmcnt(0)" ::: "memory");
    __builtin_amdgcn_sched_barrier(0);

    f32x4 acc[2][2];
#pragma unroll
    for (int m = 0; m < 2; ++m)
#pragma unroll
        for (int n = 0; n < 2; ++n) acc[m][n] = (f32x4){0.f, 0.f, 0.f, 0.f};

    const int aoff = (wm * 32 + lo) * WCOLS + hi * 8;       // A (W) m=0 base
    const int boff = (wn * 32 + lo) * F2COLS + hi * 8;      // B (F) n=0 base

    for (int t = 0; t < NTILES; ++t) {
        // wait stage(t) (issued one iteration ago, overlapped with compute(t-1))
        asm volatile("s_waitcnt vmcnt(0)" ::: "memory");
        __builtin_amdgcn_sched_barrier(0);
        __builtin_amdgcn_s_barrier();
        __builtin_amdgcn_sched_barrier(0);
        // barrier above also separates compute(t-1) readers of wt[(t+1)&1]
        // from the overwrite below -> single barrier per tile is safe.
        if (t + 1 < NTILES) stageW(t + 1);

        const unsigned short* wbase = wt[t & 1];
        int ch0 = t * 3;
        int k0  = ch0 / 9;
        int j0  = ch0 - k0 * 9;
#pragma unroll
        for (int cc = 0; cc < 3; ++cc) {
            int jj  = j0 + cc;
            int kk  = (jj >= 9) ? (k0 + 1) : k0;
            int jbb = (jj >= 9) ? (jj - 9) : jj;
            bf16x8 a0 = *(const bf16x8*)(wbase + aoff + cc * 32);
            bf16x8 a1 = *(const bf16x8*)(wbase + aoff + 16 * WCOLS + cc * 32);
            bf16x8 b0 = *(const bf16x8*)(f2t + boff + kk * F2COLS + jbb * 32);
            bf16x8 b1 = *(const bf16x8*)(f2t + boff + (16 + kk) * F2COLS + jbb * 32);
            acc[0][0] = __builtin_amdgcn_mfma_f32_16x16x32_bf16(a0, b0, acc[0][0], 0, 0, 0);
            acc[0][1] = __builtin_amdgcn_mfma_f32_16x16x32_bf16(a0, b1, acc[0][1], 0, 0, 0);
            acc[1][0] = __builtin_amdgcn_mfma_f32_16x16x32_bf16(a1, b0, acc[1][0], 0, 0, 0);
            acc[1][1] = __builtin_amdgcn_mfma_f32_16x16x32_bf16(a1, b1, acc[1][1], 0, 0, 0);
        }
    }

    // ---- epilogue: D layout col = lane&15 (l), row = (lane>>4)*4 + reg (o) ----
#pragma unroll
    for (int m = 0; m < 2; ++m) {
#pragma unroll
        for (int n = 0; n < 2; ++n) {
            int oo   = wm * 32 + m * 16 + hi * 4;
            int lcol = l0 + wn * 32 + n * 16 + lo;
            float* op = out + ((size_t)b * KOUT + oo) * LIN + lcol;
#pragma unroll
            for (int r = 0; r < 4; ++r) op[(size_t)r * LIN] = acc[m][n][r];
        }
    }
}

} // namespace

extern "C" void kernel_launch(void* const* d_in, const int* in_sizes, int n_in,
                              void* d_out, int out_size, void* d_ws, size_t ws_size,
                              hipStream_t stream) {
    const float* x             = (const float*)d_in[0];
    const float* base_w        = (const float*)d_in[1];
    const float* spline_w      = (const float*)d_in[2];
    const float* spline_scaler = (const float*)d_in[3];
    float* out = (float*)d_out;

    unsigned short* Wr = (unsigned short*)d_ws;   // 64*2592*2 = 331776 B

    kan_wprep<<<(KOUT * KIN * KW + 255) / 256, 256, 0, stream>>>(base_w, spline_w, spline_scaler, Wr);
    kan_fused<<<512, 256, 0, stream>>>(x, Wr, out);
}

// Round 5
// 25.788 us; speedup vs baseline: 1.8398x; 1.1713x over previous
//
#include <hip/hip_runtime.h>
#include <hip/hip_bf16.h>

namespace {

constexpr int KIN  = 32;    // IN_CH
constexpr int KOUT = 64;    // OUT_CH
constexpr int KW   = 9;     // KERNEL
constexpr int KPAD = 4;     // PADDING
constexpr int LIN  = 2048;
constexpr int KTOT = 2592;  // 9 taps * 288 features
constexpr int NCH  = 81;    // K-chunks of 32

typedef __bf16 bf16x8 __attribute__((ext_vector_type(8)));
typedef float  f32x4  __attribute__((ext_vector_type(4)));

__device__ __forceinline__ unsigned short f2bf(float x) {
    unsigned int u = __float_as_uint(x);
    u += 0x7FFFu + ((u >> 16) & 1u);   // RNE
    return (unsigned short)(u >> 16);
}

// ---- kernel 1: weights -> MFMA-fragment order ----
// Wf element for (o, kappa): ch=kappa/32, m=o/16, lane=(kappa%32/8)*16 + o%16,
// e=kappa%8  ->  Wf[((ch*4+m)*64 + lane)*8 + e]
// A-frag for (chunk ch, o-block m) = 64 lanes x 16B contiguous (1KB, coalesced).
__global__ __launch_bounds__(256) void kan_wprep(const float* __restrict__ base_w,
                                                 const float* __restrict__ spline_w,
                                                 const float* __restrict__ spline_scaler,
                                                 unsigned short* __restrict__ Wf) {
    int t = blockIdx.x * 256 + threadIdx.x;
    if (t >= KOUT * KIN * KW) return;
    int k = t % KW;
    int i = (t / KW) % KIN;
    int o = t / (KW * KIN);
    float sc = spline_scaler[t];
    int m  = o >> 4;
    int lo = o & 15;
#pragma unroll
    for (int c = 0; c < 9; ++c) {
        float val = (c == 0) ? base_w[t] : spline_w[(size_t)t * 8 + (c - 1)] * sc;
        int kappa = k * 288 + i * 9 + c;
        int ch = kappa >> 5;
        int hi = (kappa & 31) >> 3;
        int e  = kappa & 7;
        Wf[((size_t)(ch * 4 + m) * 64 + hi * 16 + lo) * 8 + e] = f2bf(val);
    }
}

// ---- kernel 2: fused features + barrier-free split-K MFMA GEMM ----
constexpr int BN     = 64;
constexpr int TROW   = 72;    // BN + KW - 1
constexpr int F2COLS = 296;   // 592B rows; stride 148 dw = 20 mod 32 (2-way max, free)

__global__ __launch_bounds__(256, 2) void kan_fused(const float* __restrict__ x,
                                                    const unsigned short* __restrict__ Wf,
                                                    float* __restrict__ out) {
    __shared__ char smem[65536];                       // f2t (42.6KB) / partials (64KB)
    unsigned short* f2t = (unsigned short*)smem;
    float*          red = (float*)smem;

    int tid  = threadIdx.x;
    int lane = tid & 63;
    int wv   = tid >> 6;
    int lo = lane & 15, hi = lane >> 4;

    int blk = blockIdx.x;
    int b   = blk >> 5;
    int l0  = (blk & 31) * BN;

    // ---- zero f2t (2664 x 16B) ----
    {
        f32x4 z = (f32x4){0.f, 0.f, 0.f, 0.f};
        for (int c = tid; c < TROW * F2COLS / 8; c += 256)
            *(f32x4*)(f2t + (size_t)c * 8) = z;
    }
    __syncthreads();

    // ---- features: silu + closed-form cubic B-spline, scatter to LDS ----
#pragma unroll
    for (int pass = 0; pass < 9; ++pass) {
        int unit = pass * 256 + tid;        // 2304 = 9 * 256 exactly
        int i = unit / TROW;
        int r = unit - i * TROW;
        int gx = l0 + r - KPAD;
        float v = 0.f;
        if (gx >= 0 && gx < LIN) v = x[((size_t)b * KIN + i) * LIN + gx];
        unsigned short* row = f2t + (size_t)r * F2COLS + i * 9;
        row[0] = f2bf(v / (1.f + __expf(-v)));             // silu
        float t5 = (v + 2.2f) * 2.5f;                       // knots at -2.2 + 0.4*j
        float mf = floorf(t5);
        int   m  = (int)mf;
        float u  = t5 - mf;
        float u2 = u * u, u3 = u2 * u;
        float w  = 1.f - u;
        float P0 = u3 * (1.f / 6.f);
        float P3 = w * w * w * (1.f / 6.f);
        float P1 = (1.f / 6.f) + 0.5f * u + 0.5f * u2 - 0.5f * u3;
        float P2 = (4.f / 6.f) - u2 + 0.5f * u3;
        int c0 = m - 3;
        if ((unsigned)(c0 + 0) <= 7u) row[1 + c0 + 0] = f2bf(P3);
        if ((unsigned)(c0 + 1) <= 7u) row[1 + c0 + 1] = f2bf(P2);
        if ((unsigned)(c0 + 2) <= 7u) row[1 + c0 + 2] = f2bf(P1);
        if ((unsigned)(c0 + 3) <= 7u) row[1 + c0 + 3] = f2bf(P0);
    }
    __syncthreads();

    // ---- split-K: wave wv owns chunks [ch0, ch0+nch) ----
    int nch = (wv == 0) ? 21 : 20;
    int ch0 = (wv == 0) ? 0 : wv * 20 + 1;

    f32x4 acc[4][4];
#pragma unroll
    for (int m = 0; m < 4; ++m)
#pragma unroll
        for (int n = 0; n < 4; ++n) acc[m][n] = (f32x4){0.f, 0.f, 0.f, 0.f};

    const unsigned short* wbase = Wf + (size_t)lane * 8;      // + (ch*4+m)*512
    const unsigned short* fbase = f2t + (size_t)lo * F2COLS + hi * 8;  // + (n*16+k)*F2COLS + jb*32

    // prime chunk ch0
    int ch = ch0;
    int kk = ch / 9, jb = ch - kk * 9;
    bf16x8 av[4], bv[4];
#pragma unroll
    for (int m = 0; m < 4; ++m)
        av[m] = *(const bf16x8*)(wbase + (size_t)(ch * 4 + m) * 512);
#pragma unroll
    for (int n = 0; n < 4; ++n)
        bv[n] = *(const bf16x8*)(fbase + (size_t)(n * 16 + kk) * F2COLS + jb * 32);

    for (int t = 0; t < nch; ++t) {
        int chn = (t + 1 < nch) ? ch + 1 : ch;     // last iter: harmless reload
        int kn = chn / 9, jbn = chn - kn * 9;
        bf16x8 an[4], bn[4];
#pragma unroll
        for (int m = 0; m < 4; ++m)
            an[m] = *(const bf16x8*)(wbase + (size_t)(chn * 4 + m) * 512);
#pragma unroll
        for (int n = 0; n < 4; ++n)
            bn[n] = *(const bf16x8*)(fbase + (size_t)(n * 16 + kn) * F2COLS + jbn * 32);
#pragma unroll
        for (int m = 0; m < 4; ++m)
#pragma unroll
            for (int n = 0; n < 4; ++n)
                acc[m][n] = __builtin_amdgcn_mfma_f32_16x16x32_bf16(av[m], bv[n], acc[m][n], 0, 0, 0);
#pragma unroll
        for (int m = 0; m < 4; ++m) av[m] = an[m];
#pragma unroll
        for (int n = 0; n < 4; ++n) bv[n] = bn[n];
        ch = chn;
    }

    // ---- cross-wave reduction over aliased LDS (f2t is dead now) ----
    __syncthreads();   // all waves done reading f2t
    {
        float* myp = red + (size_t)wv * 4096;
#pragma unroll
        for (int m = 0; m < 4; ++m)
#pragma unroll
            for (int n = 0; n < 4; ++n)
                *(f32x4*)(myp + ((size_t)(m * 4 + n) * 64 + lane) * 4) = acc[m][n];
    }
    __syncthreads();

    // wave wv reduces pairs p = wv*4+n  (i.e. m == wv), stores o = wv*16+hi*4+r
#pragma unroll
    for (int n = 0; n < 4; ++n) {
        int p = wv * 4 + n;
        f32x4 s = (f32x4){0.f, 0.f, 0.f, 0.f};
#pragma unroll
        for (int w = 0; w < 4; ++w)
            s += *(const f32x4*)(red + (size_t)w * 4096 + ((size_t)p * 64 + lane) * 4);
        float* op = out + ((size_t)b * KOUT + wv * 16 + hi * 4) * LIN + l0 + n * 16 + lo;
#pragma unroll
        for (int r = 0; r < 4; ++r) op[(size_t)r * LIN] = s[r];
    }
}

} // namespace

extern "C" void kernel_launch(void* const* d_in, const int* in_sizes, int n_in,
                              void* d_out, int out_size, void* d_ws, size_t ws_size,
                              hipStream_t stream) {
    const float* x             = (const float*)d_in[0];
    const float* base_w        = (const float*)d_in[1];
    const float* spline_w      = (const float*)d_in[2];
    const float* spline_scaler = (const float*)d_in[3];
    float* out = (float*)d_out;

    unsigned short* Wf = (unsigned short*)d_ws;   // 81*4*64*8 u16 = 331776 B

    kan_wprep<<<(KOUT * KIN * KW + 255) / 256, 256, 0, stream>>>(base_w, spline_w, spline_scaler, Wf);
    kan_fused<<<512, 256, 0, stream>>>(x, Wf, out);
}

// Round 6
// 23.124 us; speedup vs baseline: 2.0518x; 1.1152x over previous
//
#include <hip/hip_runtime.h>
#include <hip/hip_bf16.h>

namespace {

constexpr int KIN  = 32;    // IN_CH
constexpr int KOUT = 64;    // OUT_CH
constexpr int KW   = 9;     // KERNEL
constexpr int KPAD = 4;     // PADDING
constexpr int LIN  = 2048;
constexpr int KTOT = 2592;  // 9 taps * 288 features

typedef __bf16 bf16x8 __attribute__((ext_vector_type(8)));
typedef float  f32x4  __attribute__((ext_vector_type(4)));

__device__ __forceinline__ unsigned short f2bf(float x) {
    unsigned int u = __float_as_uint(x);
    u += 0x7FFFu + ((u >> 16) & 1u);   // RNE
    return (unsigned short)(u >> 16);
}

// ---- kernel 1: weights -> MFMA-fragment order ----
// Wf[((ch*4+m)*64 + hi*16+lo)*8 + e] = W[o=m*16+lo][kappa=ch*32+hi*8+e]
__global__ __launch_bounds__(256) void kan_wprep(const float* __restrict__ base_w,
                                                 const float* __restrict__ spline_w,
                                                 const float* __restrict__ spline_scaler,
                                                 unsigned short* __restrict__ Wf) {
    int t = blockIdx.x * 256 + threadIdx.x;
    if (t >= KOUT * KIN * KW) return;
    int k = t % KW;
    int i = (t / KW) % KIN;
    int o = t / (KW * KIN);
    float sc = spline_scaler[t];
    int m  = o >> 4;
    int lo = o & 15;
#pragma unroll
    for (int c = 0; c < 9; ++c) {
        float val = (c == 0) ? base_w[t] : spline_w[(size_t)t * 8 + (c - 1)] * sc;
        int kappa = k * 288 + i * 9 + c;
        int ch = kappa >> 5;
        int hi = (kappa & 31) >> 3;
        int e  = kappa & 7;
        Wf[((size_t)(ch * 4 + m) * 64 + hi * 16 + lo) * 8 + e] = f2bf(val);
    }
}

// ---- kernel 2: fused features + barrier-free 8-way split-K MFMA GEMM ----
constexpr int BN     = 64;
constexpr int TROW   = 72;    // BN + KW - 1
constexpr int F2COLS = 296;   // 592B rows; stride 148 dw = 20 mod 32 (2-way max, free)

__global__ __launch_bounds__(512, 4) void kan_fused(const float* __restrict__ x,
                                                    const unsigned short* __restrict__ Wf,
                                                    float* __restrict__ out) {
    __shared__ char smem[65536];                 // f2t (42.6KB) / red (64KB, aliased)
    unsigned short* f2t = (unsigned short*)smem;
    float*          red = (float*)smem;

    int tid  = threadIdx.x;
    int lane = tid & 63;
    int wv   = tid >> 6;          // 0..7
    int lo = lane & 15, hi = lane >> 4;

    int blk = blockIdx.x;
    int b   = blk >> 5;
    int l0  = (blk & 31) * BN;

    // ---- zero f2t (2664 x 16B) ----
    {
        f32x4 z = (f32x4){0.f, 0.f, 0.f, 0.f};
        for (int c = tid; c < TROW * F2COLS / 8; c += 512)
            *(f32x4*)(f2t + (size_t)c * 8) = z;
    }
    __syncthreads();

    // ---- features: silu + closed-form cubic B-spline, scatter to LDS ----
    // 2304 units = 4 full passes of 512 + tail of 256
#pragma unroll
    for (int pass = 0; pass < 5; ++pass) {
        int unit = pass * 512 + tid;
        bool ok = unit < TROW * KIN;
        int i = unit / TROW;
        int r = unit - i * TROW;
        int gx = l0 + r - KPAD;
        float v = 0.f;
        if (ok && gx >= 0 && gx < LIN) v = x[((size_t)b * KIN + i) * LIN + gx];
        if (ok) {
            unsigned short* row = f2t + (size_t)r * F2COLS + i * 9;
            row[0] = f2bf(v / (1.f + __expf(-v)));             // silu
            float t5 = (v + 2.2f) * 2.5f;                       // knots at -2.2 + 0.4*j
            float mf = floorf(t5);
            int   m  = (int)mf;
            float u  = t5 - mf;
            float u2 = u * u, u3 = u2 * u;
            float w  = 1.f - u;
            float P0 = u3 * (1.f / 6.f);
            float P3 = w * w * w * (1.f / 6.f);
            float P1 = (1.f / 6.f) + 0.5f * u + 0.5f * u2 - 0.5f * u3;
            float P2 = (4.f / 6.f) - u2 + 0.5f * u3;
            int c0 = m - 3;
            if ((unsigned)(c0 + 0) <= 7u) row[1 + c0 + 0] = f2bf(P3);
            if ((unsigned)(c0 + 1) <= 7u) row[1 + c0 + 1] = f2bf(P2);
            if ((unsigned)(c0 + 2) <= 7u) row[1 + c0 + 2] = f2bf(P1);
            if ((unsigned)(c0 + 3) <= 7u) row[1 + c0 + 3] = f2bf(P0);
        }
    }
    __syncthreads();

    // ---- 8-way split-K: wave wv owns chunks [ch0, ch0+nch) of 81 ----
    int nch = (wv == 0) ? 11 : 10;
    int ch0 = (wv == 0) ? 0 : 10 * wv + 1;

    f32x4 acc[4][4];
#pragma unroll
    for (int m = 0; m < 4; ++m)
#pragma unroll
        for (int n = 0; n < 4; ++n) acc[m][n] = (f32x4){0.f, 0.f, 0.f, 0.f};

    int kk = ch0 / 9;
    int jb = ch0 - kk * 9;
    const unsigned short* wptr = Wf + (size_t)ch0 * 2048 + (size_t)lane * 8;
    const unsigned short* fptr = f2t + (size_t)(lo + kk) * F2COLS + jb * 32 + hi * 8;

    for (int t = 0; t < nch; ++t) {
        bf16x8 a0 = *(const bf16x8*)(wptr);
        bf16x8 a1 = *(const bf16x8*)(wptr + 512);
        bf16x8 a2 = *(const bf16x8*)(wptr + 1024);
        bf16x8 a3 = *(const bf16x8*)(wptr + 1536);
        bf16x8 b0 = *(const bf16x8*)(fptr);
        bf16x8 b1 = *(const bf16x8*)(fptr + 16 * F2COLS);
        bf16x8 b2 = *(const bf16x8*)(fptr + 32 * F2COLS);
        bf16x8 b3 = *(const bf16x8*)(fptr + 48 * F2COLS);
        __builtin_amdgcn_s_setprio(1);
        acc[0][0] = __builtin_amdgcn_mfma_f32_16x16x32_bf16(a0, b0, acc[0][0], 0, 0, 0);
        acc[0][1] = __builtin_amdgcn_mfma_f32_16x16x32_bf16(a0, b1, acc[0][1], 0, 0, 0);
        acc[0][2] = __builtin_amdgcn_mfma_f32_16x16x32_bf16(a0, b2, acc[0][2], 0, 0, 0);
        acc[0][3] = __builtin_amdgcn_mfma_f32_16x16x32_bf16(a0, b3, acc[0][3], 0, 0, 0);
        acc[1][0] = __builtin_amdgcn_mfma_f32_16x16x32_bf16(a1, b0, acc[1][0], 0, 0, 0);
        acc[1][1] = __builtin_amdgcn_mfma_f32_16x16x32_bf16(a1, b1, acc[1][1], 0, 0, 0);
        acc[1][2] = __builtin_amdgcn_mfma_f32_16x16x32_bf16(a1, b2, acc[1][2], 0, 0, 0);
        acc[1][3] = __builtin_amdgcn_mfma_f32_16x16x32_bf16(a1, b3, acc[1][3], 0, 0, 0);
        acc[2][0] = __builtin_amdgcn_mfma_f32_16x16x32_bf16(a2, b0, acc[2][0], 0, 0, 0);
        acc[2][1] = __builtin_amdgcn_mfma_f32_16x16x32_bf16(a2, b1, acc[2][1], 0, 0, 0);
        acc[2][2] = __builtin_amdgcn_mfma_f32_16x16x32_bf16(a2, b2, acc[2][2], 0, 0, 0);
        acc[2][3] = __builtin_amdgcn_mfma_f32_16x16x32_bf16(a2, b3, acc[2][3], 0, 0, 0);
        acc[3][0] = __builtin_amdgcn_mfma_f32_16x16x32_bf16(a3, b0, acc[3][0], 0, 0, 0);
        acc[3][1] = __builtin_amdgcn_mfma_f32_16x16x32_bf16(a3, b1, acc[3][1], 0, 0, 0);
        acc[3][2] = __builtin_amdgcn_mfma_f32_16x16x32_bf16(a3, b2, acc[3][2], 0, 0, 0);
        acc[3][3] = __builtin_amdgcn_mfma_f32_16x16x32_bf16(a3, b3, acc[3][3], 0, 0, 0);
        __builtin_amdgcn_s_setprio(0);
        wptr += 2048;
        jb += 1;
        fptr += (jb == 9) ? (F2COLS - 8 * 32) : 32;   // wrap: next tap row, j=0
        if (jb == 9) jb = 0;
    }

    // ---- 8-way cross-wave reduction, two 64KB phases over dead f2t ----
    __syncthreads();   // all waves done reading f2t
#pragma unroll
    for (int mp = 0; mp < 2; ++mp) {
#pragma unroll
        for (int dm = 0; dm < 2; ++dm)
#pragma unroll
            for (int n = 0; n < 4; ++n)
                *(f32x4*)(red + (((size_t)wv * 8 + dm * 4 + n) * 64 + lane) * 4) = acc[mp * 2 + dm][n];
        __syncthreads();
        {
            int dm = wv >> 2, n = wv & 3;
            f32x4 s = (f32x4){0.f, 0.f, 0.f, 0.f};
#pragma unroll
            for (int w = 0; w < 8; ++w)
                s += *(const f32x4*)(red + (((size_t)w * 8 + dm * 4 + n) * 64 + lane) * 4);
            int o = (mp * 2 + dm) * 16 + hi * 4;
            float* op = out + ((size_t)b * KOUT + o) * LIN + l0 + n * 16 + lo;
            op[0]          = s[0];
            op[LIN]        = s[1];
            op[2 * LIN]    = s[2];
            op[3 * (size_t)LIN] = s[3];
        }
        if (mp == 0) __syncthreads();
    }
}

} // namespace

extern "C" void kernel_launch(void* const* d_in, const int* in_sizes, int n_in,
                              void* d_out, int out_size, void* d_ws, size_t ws_size,
                              hipStream_t stream) {
    const float* x             = (const float*)d_in[0];
    const float* base_w        = (const float*)d_in[1];
    const float* spline_w      = (const float*)d_in[2];
    const float* spline_scaler = (const float*)d_in[3];
    float* out = (float*)d_out;

    unsigned short* Wf = (unsigned short*)d_ws;   // 81*4*64*8 u16 = 331776 B

    kan_wprep<<<(KOUT * KIN * KW + 255) / 256, 256, 0, stream>>>(base_w, spline_w, spline_scaler, Wf);
    kan_fused<<<512, 512, 0, stream>>>(x, Wf, out);
}